// Round 1
// baseline (74.208 us; speedup 1.0000x reference)
//
#include <hip/hip_runtime.h>
#include <math.h>

// ChADALINE: out[b,o] = sigmoid( (sum_i x[b,i]*W[i,o] + sum_i bias[i,o]) / IN )
// (Choquet integral with cardinality measure == arithmetic mean; sort eliminated.)

#define BATCH   256
#define IN_DIM  1024
#define OUT_DIM 1024

#define TM 64   // batch rows per block
#define TN 32   // out cols per block
#define TK 64   // k chunk per staging round

#define ALD 72  // padded leading dim (bf16 elems) for A tile rows (64 + 8)
#define BLD 72  // padded leading dim for B tile rows

typedef __bf16 bf16x8 __attribute__((ext_vector_type(8)));
typedef float  f32x4  __attribute__((ext_vector_type(4)));

__global__ __launch_bounds__(256) void chadaline_kernel(
    const float* __restrict__ x,     // [BATCH, IN_DIM]
    const float* __restrict__ w,     // [IN_DIM, OUT_DIM]
    const float* __restrict__ bias,  // [IN_DIM, OUT_DIM]
    float* __restrict__ out)         // [BATCH, OUT_DIM]
{
    __shared__ __bf16 Alds[TM * ALD];        // A tile: [m][k], bf16
    __shared__ __bf16 Blds[TN * BLD];        // B tile transposed: [n][k], bf16
    __shared__ float  bias_red[8][TN];
    __shared__ float  colsum[TN];

    const int t    = threadIdx.x;
    const int lane = t & 63;
    const int wave = t >> 6;          // 0..3, wave handles rows 16*wave..+15
    const int quad = lane >> 4;       // 0..3
    const int l16  = lane & 15;

    const int bm = blockIdx.y * TM;   // batch tile origin
    const int on = blockIdx.x * TN;   // out-col tile origin

    // staging assignments
    const int am = t >> 2;            // 0..63  (A tile row)
    const int ak = (t & 3) * 16;      // 0,16,32,48 (A tile k offset, 16 elems each)
    const int bn = t & 31;            // 0..31  (B tile col = out col)
    const int bk = (t >> 5) * 8;      // 0..56  (B tile k offset, 8 elems each)

    float bias_acc = 0.f;
    f32x4 acc0 = {0.f, 0.f, 0.f, 0.f};
    f32x4 acc1 = {0.f, 0.f, 0.f, 0.f};

    for (int k0 = 0; k0 < IN_DIM; k0 += TK) {
        // ---- stage A: x[bm+am][k0+ak .. +15] -> bf16 LDS (row-major [m][k])
        const float* xa = x + (size_t)(bm + am) * IN_DIM + k0 + ak;
        const float4 a0 = *(const float4*)(xa + 0);
        const float4 a1 = *(const float4*)(xa + 4);
        const float4 a2 = *(const float4*)(xa + 8);
        const float4 a3 = *(const float4*)(xa + 12);
        bf16x8 v0, v1;
        v0[0] = (__bf16)a0.x; v0[1] = (__bf16)a0.y; v0[2] = (__bf16)a0.z; v0[3] = (__bf16)a0.w;
        v0[4] = (__bf16)a1.x; v0[5] = (__bf16)a1.y; v0[6] = (__bf16)a1.z; v0[7] = (__bf16)a1.w;
        v1[0] = (__bf16)a2.x; v1[1] = (__bf16)a2.y; v1[2] = (__bf16)a2.z; v1[3] = (__bf16)a2.w;
        v1[4] = (__bf16)a3.x; v1[5] = (__bf16)a3.y; v1[6] = (__bf16)a3.z; v1[7] = (__bf16)a3.w;
        *(bf16x8*)(&Alds[am * ALD + ak])     = v0;
        *(bf16x8*)(&Alds[am * ALD + ak + 8]) = v1;

        // ---- stage B (transposed): W[k0+bk+j][on+bn] -> Blds[n][k]
        const float* wb = w + (size_t)(k0 + bk) * OUT_DIM + on + bn;
        bf16x8 bv;
        #pragma unroll
        for (int j = 0; j < 8; ++j) bv[j] = (__bf16)wb[(size_t)j * OUT_DIM];
        *(bf16x8*)(&Blds[bn * BLD + bk]) = bv;

        // ---- bias column partial sums (fp32, no LDS staging needed)
        const float* bb = bias + (size_t)(k0 + bk) * OUT_DIM + on + bn;
        #pragma unroll
        for (int j = 0; j < 8; ++j) bias_acc += bb[(size_t)j * OUT_DIM];

        __syncthreads();

        // ---- MFMA: wave computes rows [16*wave, 16*wave+16) x all 32 cols
        const __bf16* abase  = &Alds[(wave * 16 + l16) * ALD + quad * 8];
        const __bf16* bbase0 = &Blds[(l16) * BLD + quad * 8];
        const __bf16* bbase1 = &Blds[(16 + l16) * BLD + quad * 8];
        #pragma unroll
        for (int s = 0; s < 2; ++s) {
            bf16x8 af  = *(const bf16x8*)(abase  + s * 32);
            bf16x8 bf0 = *(const bf16x8*)(bbase0 + s * 32);
            bf16x8 bf1 = *(const bf16x8*)(bbase1 + s * 32);
            acc0 = __builtin_amdgcn_mfma_f32_16x16x32_bf16(af, bf0, acc0, 0, 0, 0);
            acc1 = __builtin_amdgcn_mfma_f32_16x16x32_bf16(af, bf1, acc1, 0, 0, 0);
        }
        __syncthreads();
    }

    // ---- reduce bias partial sums: 8 threads per column
    bias_red[t >> 5][t & 31] = bias_acc;
    __syncthreads();
    if (t < TN) {
        float s = 0.f;
        #pragma unroll
        for (int r = 0; r < 8; ++r) s += bias_red[r][t];
        colsum[t] = s;
    }
    __syncthreads();

    // ---- epilogue: chi = (acc + colsum)/IN, out = sigmoid(chi)
    const float inv_n = 1.0f / (float)IN_DIM;
    #pragma unroll
    for (int j = 0; j < 2; ++j) {
        f32x4 a = (j == 0) ? acc0 : acc1;
        const int   col = on + j * 16 + l16;
        const float cs  = colsum[j * 16 + l16];
        #pragma unroll
        for (int r = 0; r < 4; ++r) {
            const int row = bm + wave * 16 + quad * 4 + r;
            const float v = (a[r] + cs) * inv_n;
            out[(size_t)row * OUT_DIM + col] = 1.0f / (1.0f + __expf(-v));
        }
    }
}

extern "C" void kernel_launch(void* const* d_in, const int* in_sizes, int n_in,
                              void* d_out, int out_size, void* d_ws, size_t ws_size,
                              hipStream_t stream) {
    const float* x  = (const float*)d_in[0];
    const float* w  = (const float*)d_in[1];
    const float* b  = (const float*)d_in[2];
    float* out = (float*)d_out;

    dim3 grid(OUT_DIM / TN, BATCH / TM);   // (32, 4) = 128 blocks
    chadaline_kernel<<<grid, 256, 0, stream>>>(x, w, b, out);
}

// Round 2
// 71.745 us; speedup vs baseline: 1.0343x; 1.0343x over previous
//
#include <hip/hip_runtime.h>
#include <math.h>

// ChADALINE: out[b,o] = sigmoid( (sum_i x[b,i]*W[i,o] + sum_i bias[i,o]) / IN )
// Choquet integral w/ cardinality measure == arithmetic mean; sort eliminated.
//
// R2: 256 blocks (1/CU), TK=256 (4 K-iters), register prefetch across barriers,
// bias colsum in VALU registers (no LDS staging), wave-per-16x16-quadrant.

#define BATCH   256
#define IN_DIM  1024
#define OUT_DIM 1024

#define TM 32
#define TN 32
#define TK 256
#define KITERS (IN_DIM / TK)   // 4
#define LDK (TK + 8)           // 264 elems: 528B row stride == 4 banks mod 32 -> balanced

typedef __bf16 bf16x8 __attribute__((ext_vector_type(8)));
typedef float  f32x4  __attribute__((ext_vector_type(4)));

__global__ __launch_bounds__(256) void chadaline_kernel(
    const float* __restrict__ x,     // [BATCH, IN_DIM]
    const float* __restrict__ w,     // [IN_DIM, OUT_DIM]
    const float* __restrict__ bias,  // [IN_DIM, OUT_DIM]
    float* __restrict__ out)         // [BATCH, OUT_DIM]
{
    __shared__ __bf16 Alds[TM * LDK];     // [row][k] bf16, 16.9 KB
    __shared__ __bf16 Blds[TN * LDK];     // [n][k]   bf16, 16.9 KB
    __shared__ float  bias_red[16][TN];   // 2 KB

    const int t    = threadIdx.x;
    const int lane = t & 63;
    const int wv   = t >> 6;          // 0..3
    const int quad = lane >> 4;       // 0..3
    const int l16  = lane & 15;
    const int tm   = wv & 1;          // row quadrant
    const int tn   = wv >> 1;         // col quadrant

    const int bm = blockIdx.y * TM;
    const int on = blockIdx.x * TN;

    // staging assignments
    const int arow  = t >> 3;         // 0..31 : A row
    const int acol0 = (t & 7) * 16;   // A k offset (coalesced 128B per 8 lanes)
    const int np    = t & 15;         // W/bias col pair: cols 2np, 2np+1
    const int kg    = t >> 4;         // 0..15 : W/bias k subgroup (16 rows each)

    const float* xrow = x    + (size_t)(bm + arow) * IN_DIM + acol0;
    const float* wcol = w    + (size_t)(kg * 16) * OUT_DIM + on + 2 * np;
    const float* bcol = bias + (size_t)(kg * 16) * OUT_DIM + on + 2 * np;

    float4 ra[8];    // A prefetch: 32 k-elems (2 groups of 16 at +0, +128)
    float2 rw[16];   // W prefetch: 16 rows x 2 cols

    // ---- prefetch iter 0
    #pragma unroll
    for (int i = 0; i < 2; ++i)
        #pragma unroll
        for (int jj = 0; jj < 4; ++jj)
            ra[i * 4 + jj] = *(const float4*)(xrow + i * 128 + jj * 4);
    #pragma unroll
    for (int j = 0; j < 16; ++j)
        rw[j] = *(const float2*)(wcol + (size_t)j * OUT_DIM);

    f32x4 acc = {0.f, 0.f, 0.f, 0.f};
    float bx = 0.f, by = 0.f;

    for (int it = 0; it < KITERS; ++it) {
        // ---- LDS stores from prefetched regs (convert fp32 -> bf16)
        #pragma unroll
        for (int i = 0; i < 2; ++i) {
            bf16x8 v0, v1;
            const float4 a0 = ra[i * 4 + 0], a1 = ra[i * 4 + 1];
            const float4 a2 = ra[i * 4 + 2], a3 = ra[i * 4 + 3];
            v0[0] = (__bf16)a0.x; v0[1] = (__bf16)a0.y; v0[2] = (__bf16)a0.z; v0[3] = (__bf16)a0.w;
            v0[4] = (__bf16)a1.x; v0[5] = (__bf16)a1.y; v0[6] = (__bf16)a1.z; v0[7] = (__bf16)a1.w;
            v1[0] = (__bf16)a2.x; v1[1] = (__bf16)a2.y; v1[2] = (__bf16)a2.z; v1[3] = (__bf16)a2.w;
            v1[4] = (__bf16)a3.x; v1[5] = (__bf16)a3.y; v1[6] = (__bf16)a3.z; v1[7] = (__bf16)a3.w;
            *(bf16x8*)&Alds[arow * LDK + acol0 + i * 128]     = v0;
            *(bf16x8*)&Alds[arow * LDK + acol0 + i * 128 + 8] = v1;
        }
        #pragma unroll
        for (int h = 0; h < 2; ++h) {
            bf16x8 c0, c1;
            #pragma unroll
            for (int j = 0; j < 8; ++j) {
                c0[j] = (__bf16)rw[h * 8 + j].x;
                c1[j] = (__bf16)rw[h * 8 + j].y;
            }
            *(bf16x8*)&Blds[(2 * np + 0) * LDK + kg * 16 + h * 8] = c0;
            *(bf16x8*)&Blds[(2 * np + 1) * LDK + kg * 16 + h * 8] = c1;
        }

        // ---- prefetch next iter (register dest: NOT drained by s_barrier,
        //      lands during the MFMA phase below)
        if (it + 1 < KITERS) {
            const float* xn = xrow + (size_t)(it + 1) * TK;
            #pragma unroll
            for (int i = 0; i < 2; ++i)
                #pragma unroll
                for (int jj = 0; jj < 4; ++jj)
                    ra[i * 4 + jj] = *(const float4*)(xn + i * 128 + jj * 4);
            const float* wn = wcol + (size_t)(it + 1) * TK * OUT_DIM;
            #pragma unroll
            for (int j = 0; j < 16; ++j)
                rw[j] = *(const float2*)(wn + (size_t)j * OUT_DIM);
        }

        // ---- bias column partial sums (pure VALU, no LDS)
        {
            const float* bn = bcol + (size_t)it * TK * OUT_DIM;
            #pragma unroll
            for (int j = 0; j < 16; ++j) {
                const float2 v = *(const float2*)(bn + (size_t)j * OUT_DIM);
                bx += v.x; by += v.y;
            }
        }

        __syncthreads();

        // ---- MFMA: wave (tm,tn) does its 16x16 quadrant over this K chunk
        const __bf16* ab = &Alds[(tm * 16 + l16) * LDK + quad * 8];
        const __bf16* bb = &Blds[(tn * 16 + l16) * LDK + quad * 8];
        #pragma unroll
        for (int s = 0; s < 8; ++s) {
            bf16x8 af = *(const bf16x8*)(ab + s * 32);
            bf16x8 bf = *(const bf16x8*)(bb + s * 32);
            acc = __builtin_amdgcn_mfma_f32_16x16x32_bf16(af, bf, acc, 0, 0, 0);
        }
        __syncthreads();
    }

    // ---- bias colsum reduce
    bias_red[kg][2 * np]     = bx;
    bias_red[kg][2 * np + 1] = by;
    __syncthreads();

    const int c16 = tn * 16 + l16;
    float cs = 0.f;
    #pragma unroll
    for (int r = 0; r < 16; ++r) cs += bias_red[r][c16];

    // ---- epilogue: chi = (acc + colsum)/IN, out = sigmoid(chi)
    const float inv_n = 1.0f / (float)IN_DIM;
    const int col = on + c16;
    #pragma unroll
    for (int r = 0; r < 4; ++r) {
        const int row = bm + tm * 16 + quad * 4 + r;
        const float v = (acc[r] + cs) * inv_n;
        out[(size_t)row * OUT_DIM + col] = 1.0f / (1.0f + __expf(-v));
    }
}

extern "C" void kernel_launch(void* const* d_in, const int* in_sizes, int n_in,
                              void* d_out, int out_size, void* d_ws, size_t ws_size,
                              hipStream_t stream) {
    const float* x  = (const float*)d_in[0];
    const float* w  = (const float*)d_in[1];
    const float* b  = (const float*)d_in[2];
    float* out = (float*)d_out;

    dim3 grid(OUT_DIM / TN, BATCH / TM);   // (32, 8) = 256 blocks, 1 per CU
    chadaline_kernel<<<grid, 256, 0, stream>>>(x, w, b, out);
}

// Round 3
// 70.581 us; speedup vs baseline: 1.0514x; 1.0165x over previous
//
#include <hip/hip_runtime.h>
#include <math.h>

// ChADALINE: out[b,o] = sigmoid( (sum_i x[b,i]*W[i,o] + sum_i bias[i,o]) / IN )
// Choquet integral w/ cardinality measure == arithmetic mean; sort eliminated.
//
// R3: two-phase. prep: fp32->bf16 convert + pack x/W into exact MFMA fragment
// order + bias column partial sums (bandwidth-trivial). gemm: fragments loaded
// straight from global to VGPRs (no LDS staging, no K-loop barriers), split-K-4
// per 16x16 tile -> 4096 waves (16 waves/CU), LDS reduce + sigmoid epilogue.

#define BATCH   256
#define IN_DIM  1024
#define OUT_DIM 1024

// ws layout (bytes)
#define APACK_OFF 0                    // [16 mt][32 s][64 lane][8] bf16 = 512 KB
#define WPACK_OFF (512 * 1024)         // [64 nt][32 s][64 lane][8] bf16 = 2 MB
#define BPART_OFF (2560 * 1024)        // [16 rc][1024 col] f32 = 64 KB

#define NWTASK_A   512                 // 16 mt * 32 s
#define NWTASK_W  2048                 // 64 nt * 32 s
#define NWTASK_B   256                 // 16 rc * 16 cc
#define NBLK_PREP ((NWTASK_A + NWTASK_W + NWTASK_B) / 4)   // 704

typedef __bf16 bf16x8 __attribute__((ext_vector_type(8)));
typedef float  f32x4  __attribute__((ext_vector_type(4)));

__global__ __launch_bounds__(256) void chad_prep(
    const float* __restrict__ x,     // [BATCH, IN_DIM]
    const float* __restrict__ w,     // [IN_DIM, OUT_DIM]
    const float* __restrict__ bias,  // [IN_DIM, OUT_DIM]
    unsigned char* __restrict__ ws)
{
    __bf16* apack = (__bf16*)(ws + APACK_OFF);
    __bf16* wpack = (__bf16*)(ws + WPACK_OFF);
    float*  bpart = (float*)(ws + BPART_OFF);

    const int t    = threadIdx.x;
    const int lane = t & 63;
    const int wv   = t >> 6;
    const int g    = blockIdx.x * 4 + wv;   // global wave-task id
    const int l16  = lane & 15;
    const int quad = lane >> 4;

    if (g < NWTASK_A) {
        // pack x[mt*16 + (lane&15)][s*32 + quad*8 + j] -> apack[g][lane][j]
        const int mt = g >> 5, s = g & 31;
        const float* src = x + (size_t)(mt * 16 + l16) * IN_DIM + s * 32 + quad * 8;
        const float4 v0 = *(const float4*)src;
        const float4 v1 = *(const float4*)(src + 4);
        bf16x8 o;
        o[0] = (__bf16)v0.x; o[1] = (__bf16)v0.y; o[2] = (__bf16)v0.z; o[3] = (__bf16)v0.w;
        o[4] = (__bf16)v1.x; o[5] = (__bf16)v1.y; o[6] = (__bf16)v1.z; o[7] = (__bf16)v1.w;
        *(bf16x8*)(apack + (size_t)g * 512 + lane * 8) = o;
    } else if (g < NWTASK_A + NWTASK_W) {
        // pack W[s*32 + quad*8 + j][nt*16 + (lane&15)] -> wpack[wt][lane][j]
        const int wt = g - NWTASK_A;
        const int nt = wt >> 5, s = wt & 31;
        const float* src = w + (size_t)(s * 32 + quad * 8) * OUT_DIM + nt * 16 + l16;
        bf16x8 o;
        #pragma unroll
        for (int j = 0; j < 8; ++j) o[j] = (__bf16)src[(size_t)j * OUT_DIM];
        *(bf16x8*)(wpack + (size_t)wt * 512 + lane * 8) = o;
    } else {
        // bias partial colsum: rows [rc*64, rc*64+64), col = cc*64 + lane
        const int bt = g - NWTASK_A - NWTASK_W;
        const int rc = bt >> 4, cc = bt & 15;
        const int col = cc * 64 + lane;
        const float* src = bias + (size_t)rc * 64 * OUT_DIM + col;
        float sum = 0.f;
        #pragma unroll 8
        for (int r = 0; r < 64; ++r) sum += src[(size_t)r * OUT_DIM];
        bpart[rc * OUT_DIM + col] = sum;
    }
}

__global__ __launch_bounds__(256) void chad_gemm(
    const unsigned char* __restrict__ ws,
    float* __restrict__ out)          // [BATCH, OUT_DIM]
{
    const __bf16* apack = (const __bf16*)(ws + APACK_OFF);
    const __bf16* wpack = (const __bf16*)(ws + WPACK_OFF);
    const float*  bpart = (const float*)(ws + BPART_OFF);

    __shared__ float red[4][64][4];   // [wave][lane][reg]
    __shared__ float cs_lds[16];

    const int t    = threadIdx.x;
    const int lane = t & 63;
    const int wv   = t >> 6;                 // split-K segment: s in [wv*8, wv*8+8)
    const int mt   = blockIdx.x >> 6;        // 0..15 row tile
    const int nt   = blockIdx.x & 63;        // 0..63 col tile

    const __bf16* ab = apack + ((size_t)(mt * 32 + wv * 8) * 64 + lane) * 8;
    const __bf16* bb = wpack + ((size_t)(nt * 32 + wv * 8) * 64 + lane) * 8;

    // 16 independent, perfectly-coalesced dwordx4 loads issued up front
    bf16x8 af[8], bfv[8];
    #pragma unroll
    for (int i = 0; i < 8; ++i) {
        af[i]  = *(const bf16x8*)(ab + (size_t)i * 512);
        bfv[i] = *(const bf16x8*)(bb + (size_t)i * 512);
    }

    f32x4 acc = {0.f, 0.f, 0.f, 0.f};
    #pragma unroll
    for (int i = 0; i < 8; ++i)
        acc = __builtin_amdgcn_mfma_f32_16x16x32_bf16(af[i], bfv[i], acc, 0, 0, 0);

    *(f32x4*)&red[wv][lane][0] = acc;

    if (t < 16) {   // per-block bias colsum for this tile's 16 columns
        float s = 0.f;
        #pragma unroll
        for (int p = 0; p < 16; ++p) s += bpart[p * OUT_DIM + nt * 16 + t];
        cs_lds[t] = s;
    }
    __syncthreads();

    // epilogue: thread t -> (row = t>>4, col = t&15) of the 16x16 tile.
    // C/D layout: value (row,col) lives in lane (row>>2)*16+col, reg row&3.
    const int row = t >> 4, col = t & 15;
    const int rl  = ((row >> 2) << 4) + col;
    const int rr  = row & 3;
    float v = red[0][rl][rr] + red[1][rl][rr] + red[2][rl][rr] + red[3][rl][rr];
    v = (v + cs_lds[col]) * (1.0f / (float)IN_DIM);
    out[(size_t)(mt * 16 + row) * OUT_DIM + nt * 16 + col] = 1.0f / (1.0f + __expf(-v));
}

extern "C" void kernel_launch(void* const* d_in, const int* in_sizes, int n_in,
                              void* d_out, int out_size, void* d_ws, size_t ws_size,
                              hipStream_t stream) {
    const float* x  = (const float*)d_in[0];
    const float* w  = (const float*)d_in[1];
    const float* b  = (const float*)d_in[2];
    float* out = (float*)d_out;

    chad_prep<<<NBLK_PREP, 256, 0, stream>>>(x, w, b, (unsigned char*)d_ws);
    chad_gemm<<<(BATCH / 16) * (OUT_DIM / 16), 256, 0, stream>>>(
        (const unsigned char*)d_ws, out);
}